// Round 1
// 454.878 us; speedup vs baseline: 1.0449x; 1.0449x over previous
//
#include <hip/hip_runtime.h>
#include <hip/hip_bf16.h>
#include <math.h>

#define Bn 64
#define Nn 4096
#define Dn 128
#define Sn 8
#define Hn 256
#define LN_EPS 1e-5f
#define QSCALE 0.08838834764831845f  // 1/sqrt(128), pre-applied to q

typedef __bf16 bf16x8 __attribute__((ext_vector_type(8)));
typedef float f32x4 __attribute__((ext_vector_type(4)));
typedef unsigned short ushort_t;

__device__ __forceinline__ float dot4(float4 a, float4 b) {
    return a.x*b.x + a.y*b.y + a.z*b.z + a.w*b.w;
}
__device__ __forceinline__ ushort_t f2bf(float f) {
    __bf16 b = (__bf16)f;
    ushort_t u; __builtin_memcpy(&u, &b, 2); return u;
}
__device__ __forceinline__ float bf2f(ushort_t u) {
    unsigned int x = ((unsigned int)u) << 16; float f; __builtin_memcpy(&f, &x, 4); return f;
}
__device__ __forceinline__ bf16x8 zero8() {
    bf16x8 z;
    #pragma unroll
    for (int i = 0; i < 8; ++i) z[i] = (__bf16)0.0f;
    return z;
}

// ---------------------------------------------------------------------------
// K0: slots = mu + exp(log_sigma) * noise, broadcast over batch
__global__ void k_slots_init(const float* __restrict__ mu, const float* __restrict__ ls,
                             const float* __restrict__ noise, float* __restrict__ slots) {
    int i = blockIdx.x * blockDim.x + threadIdx.x;
    if (i < Sn * Dn) {
        float v = mu[i] + __expf(ls[i]) * noise[i];
        #pragma unroll 4
        for (int b = 0; b < Bn; ++b) slots[b * Sn * Dn + i] = v;
    }
}

// ---------------------------------------------------------------------------
// Kw: pack [wk; wv] -> bf16 in MFMA A-fragment order
__global__ void k_wprep(const float* __restrict__ wk, const float* __restrict__ wv,
                        ushort_t* __restrict__ wallT) {
    int o = blockIdx.x * blockDim.x + threadIdx.x;  // 32768
    if (o < 32768) {
        int e = o & 7;
        int l = (o >> 3) & 15;
        int q = (o >> 7) & 3;
        int k = (o >> 9) & 3;
        int G = o >> 11;
        int row = G * 16 + l;
        int col = k * 32 + q * 8 + e;
        float f = (row < 128) ? wk[row * 128 + col] : wv[(row - 128) * 128 + col];
        wallT[o] = f2bf(f);
    }
}

// ---------------------------------------------------------------------------
// K1: LN + K/V projection.
// v2: wallT staged ONCE per block into LDS (64 KiB, identical linear layout),
// 512-thread blocks own 128 rows (8 waves x 16). Kills the per-wave 64 KB
// L2 re-read (1 GB aggregate -> 134 MB) and converts the inner-loop operand
// fetch from vmcnt-latency-bound global loads to pipelined ds_read_b128.
// Per-wave row/LN/MFMA/store logic unchanged.
__global__ __launch_bounds__(512) void k_lnkv_mfma(
    const float* __restrict__ inp, const float* __restrict__ ni_g, const float* __restrict__ ni_b,
    const ushort_t* __restrict__ wallT, const float* __restrict__ bk, const float* __restrict__ bv,
    ushort_t* __restrict__ kout, ushort_t* __restrict__ vout)
{
    __shared__ ushort_t wsh[32768];                // 64 KiB, linear copy of wallT
    const int t = threadIdx.x;
    const int lane = t & 63;
    const int w = t >> 6;                          // 0..7
    const int l15 = lane & 15, q = lane >> 4;
    const int rowbase = blockIdx.x * 128;          // 2048 blocks
    const int row = rowbase + w * 16 + l15;
    const int b_idx = rowbase >> 12;

    // stage wallT -> LDS: 512 thr * 8 iters * 16 B = 64 KiB
    #pragma unroll
    for (int i = 0; i < 8; ++i) {
        int off = (i * 512 + t) * 8;               // ushort units
        *(bf16x8*)&wsh[off] = *(const bf16x8*)&wallT[off];
    }

    const float* xr = inp + (size_t)row * Dn + q * 8;
    float4 xv[8];
    #pragma unroll
    for (int c = 0; c < 4; ++c) {
        xv[2*c]   = *(const float4*)(xr + c * 32);
        xv[2*c+1] = *(const float4*)(xr + c * 32 + 4);
    }
    float s = 0.f, sq = 0.f;
    #pragma unroll
    for (int i = 0; i < 8; ++i) {
        float4 x4 = xv[i];
        s  += x4.x + x4.y + x4.z + x4.w;
        sq += x4.x*x4.x + x4.y*x4.y + x4.z*x4.z + x4.w*x4.w;
    }
    s  += __shfl_xor(s, 16);  s  += __shfl_xor(s, 32);
    sq += __shfl_xor(sq, 16); sq += __shfl_xor(sq, 32);
    float mu = s * (1.0f / 128.0f);
    float rs = rsqrtf(sq * (1.0f / 128.0f) - mu * mu + LN_EPS);

    // normalize into B-fragments (lane already holds exactly frag footprint)
    bf16x8 xf[4];
    #pragma unroll
    for (int c = 0; c < 4; ++c) {
        const float* gp = ni_g + c * 32 + q * 8;
        const float* bp = ni_b + c * 32 + q * 8;
        float4 g0 = *(const float4*)gp, g1 = *(const float4*)(gp + 4);
        float4 b0 = *(const float4*)bp, b1 = *(const float4*)(bp + 4);
        bf16x8 f;
        f[0] = (__bf16)((xv[2*c].x   - mu) * rs * g0.x + b0.x);
        f[1] = (__bf16)((xv[2*c].y   - mu) * rs * g0.y + b0.y);
        f[2] = (__bf16)((xv[2*c].z   - mu) * rs * g0.z + b0.z);
        f[3] = (__bf16)((xv[2*c].w   - mu) * rs * g0.w + b0.w);
        f[4] = (__bf16)((xv[2*c+1].x - mu) * rs * g1.x + b1.x);
        f[5] = (__bf16)((xv[2*c+1].y - mu) * rs * g1.y + b1.y);
        f[6] = (__bf16)((xv[2*c+1].z - mu) * rs * g1.z + b1.z);
        f[7] = (__bf16)((xv[2*c+1].w - mu) * rs * g1.w + b1.w);
        xf[c] = f;
    }

    __syncthreads();   // wsh ready

    const int nloc0 = (rowbase & 4095) + w * 16 + q * 4;
    #pragma unroll
    for (int ct = 0; ct < 16; ++ct) {
        bf16x8 af[4];
        #pragma unroll
        for (int k4 = 0; k4 < 4; ++k4)
            af[k4] = *(const bf16x8*)&wsh[((ct * 4 + k4) * 64 + lane) * 8];
        f32x4 acc = {0.f, 0.f, 0.f, 0.f};
        if (ct < 8) {
            #pragma unroll
            for (int k4 = 0; k4 < 4; ++k4)
                acc = __builtin_amdgcn_mfma_f32_16x16x32_bf16(af[k4], xf[k4], acc, 0, 0, 0);
            // lane stores k[n=row][d0..d0+3], d0 = ct*16 + q*4
            int d0 = ct * 16 + q * 4;
            float4 bia = *(const float4*)&bk[d0];
            ushort4 o = { f2bf(acc[0] + bia.x), f2bf(acc[1] + bia.y),
                          f2bf(acc[2] + bia.z), f2bf(acc[3] + bia.w) };
            size_t off = ((size_t)(((rowbase >> 4) + w) * 4 + (d0 >> 5)) * 64
                          + ((d0 >> 3) & 3) * 16 + l15) * 8 + (d0 & 7);
            *(ushort4*)&kout[off] = o;
        } else {
            #pragma unroll
            for (int k4 = 0; k4 < 4; ++k4)
                acc = __builtin_amdgcn_mfma_f32_16x16x32_bf16(xf[k4], af[k4], acc, 0, 0, 0);
            // lane stores v[d = dgrp*16+l15][n0..n0+3], n0 = nloc0
            int dgrp = ct - 8;
            float bb = bv[dgrp * 16 + l15];
            ushort4 o = { f2bf(acc[0] + bb), f2bf(acc[1] + bb),
                          f2bf(acc[2] + bb), f2bf(acc[3] + bb) };
            size_t off = (((size_t)(b_idx * 8 + dgrp) * 128 + (nloc0 >> 5)) * 64
                          + ((nloc0 >> 3) & 3) * 16 + l15) * 8 + (nloc0 & 7);
            *(ushort4*)&vout[off] = o;
        }
    }
}

// ---------------------------------------------------------------------------
// K2: initial q = LN(slots)@wq.T + bq, bf16 pre-scaled. 64 blocks x 256 thr.
__global__ __launch_bounds__(256) void k_qproj2(
    const float* __restrict__ slots, const float* __restrict__ ns_g, const float* __restrict__ ns_b,
    const float* __restrict__ wq, const float* __restrict__ bq,
    ushort_t* __restrict__ qb)
{
    __shared__ float lnq[8][128];
    const int t = threadIdx.x;
    const int bs0 = blockIdx.x * 8;
    {
        int r = t >> 5, c = (t & 31) * 4;
        float4 x4 = *(const float4*)&slots[(size_t)(bs0 + r) * Dn + c];
        float s  = x4.x + x4.y + x4.z + x4.w;
        float sq = x4.x*x4.x + x4.y*x4.y + x4.z*x4.z + x4.w*x4.w;
        #pragma unroll
        for (int m = 1; m <= 16; m <<= 1) { s += __shfl_xor(s, m); sq += __shfl_xor(sq, m); }
        float mu = s * (1.0f / 128.0f);
        float rs = rsqrtf(sq * (1.0f / 128.0f) - mu * mu + LN_EPS);
        lnq[r][c+0] = (x4.x - mu) * rs * ns_g[c+0] + ns_b[c+0];
        lnq[r][c+1] = (x4.y - mu) * rs * ns_g[c+1] + ns_b[c+1];
        lnq[r][c+2] = (x4.z - mu) * rs * ns_g[c+2] + ns_b[c+2];
        lnq[r][c+3] = (x4.w - mu) * rs * ns_g[c+3] + ns_b[c+3];
    }
    __syncthreads();
    {
        int c = t & 127, rb = (t >> 7) * 4;
        const float* W = wq + (size_t)c * Dn;
        float acc[4] = {0.f, 0.f, 0.f, 0.f};
        for (int d = 0; d < 128; d += 4) {
            float4 w4 = *(const float4*)(W + d);
            #pragma unroll
            for (int rr = 0; rr < 4; ++rr) acc[rr] += dot4(w4, *(const float4*)&lnq[rb + rr][d]);
        }
        float bb = bq[c];
        #pragma unroll
        for (int rr = 0; rr < 4; ++rr)
            qb[(size_t)(bs0 + rb + rr) * Dn + c] = f2bf((acc[rr] + bb) * QSCALE);
    }
}

// ---------------------------------------------------------------------------
// K3: MFMA attention, barrier-free waves. grid (8 chunks, 64 b), 512 thr
// (8 waves), each wave owns 64 n. QK operand-swapped (D[n][s]); softmax over
// s via shfl_xor(1/2/4); P->A-operand via in-register shuffle transpose;
// PV partials per wave; ONE final LDS reduction.
// v2: V-fragment loads issued BEFORE softmax/transpose so the shuffle chains
// hide the V fetch latency.
__global__ __launch_bounds__(512) void k_attn_mfma(
    const ushort_t* __restrict__ kbuf, const ushort_t* __restrict__ vtbuf,
    const ushort_t* __restrict__ qb,
    float* __restrict__ upart, float* __restrict__ npart)
{
    __shared__ float ush[8][8][128];   // 32 KiB
    __shared__ float nsh[8][8];
    const int t = threadIdx.x;
    const int b = blockIdx.y;
    const int chunk = blockIdx.x;      // 0..7
    const int lane = t & 63;
    const int w = t >> 6;
    const int l15 = lane & 15, q = lane >> 4;
    const int srcA = ((lane & 16) << 1) | l15;   // 32*(qt&1) + l15
    const bool hi = lane >= 32;                  // qt>>1

    bf16x8 aq[4];
    #pragma unroll
    for (int c = 0; c < 4; ++c) {
        bf16x8 z = zero8();
        if (l15 < 8)
            z = *(const bf16x8*)&qb[((size_t)b * Sn + l15) * Dn + c * 32 + q * 8];
        aq[c] = z;
    }

    f32x4 acc[8];
    #pragma unroll
    for (int dg = 0; dg < 8; ++dg) acc[dg] = (f32x4){0.f, 0.f, 0.f, 0.f};
    float nacc = 0.f;

    #pragma unroll
    for (int u = 0; u < 2; ++u) {
        const int n32 = chunk * 512 + w * 64 + u * 32;   // n within batch
        const int ng = n32 >> 4;
        const int nc = n32 >> 5;

        // QK^T for both 16-row groups
        f32x4 lg2[2];
        #pragma unroll
        for (int T = 0; T < 2; ++T) {
            f32x4 lg = {0.f, 0.f, 0.f, 0.f};
            #pragma unroll
            for (int c = 0; c < 4; ++c) {
                bf16x8 kf = *(const bf16x8*)&kbuf[(((size_t)b * 256 + ng + T) * 4 + c) * 512 + lane * 8];
                lg = __builtin_amdgcn_mfma_f32_16x16x32_bf16(kf, aq[c], lg, 0, 0, 0);
            }
            lg2[T] = lg;
        }

        // issue V loads now -- softmax below hides their latency
        bf16x8 bvf[8];
        #pragma unroll
        for (int dg = 0; dg < 8; ++dg)
            bvf[dg] = *(const bf16x8*)&vtbuf[(((size_t)b * 8 + dg) * 128 + nc) * 512 + lane * 8];

        // softmax over s (lane quads), per n-row
        float p0[4], p1[4];
        #pragma unroll
        for (int T = 0; T < 2; ++T) {
            float* pp = T ? p1 : p0;
            #pragma unroll
            for (int r = 0; r < 4; ++r) {
                float m = lg2[T][r];
                m = fmaxf(m, __shfl_xor(m, 1));
                m = fmaxf(m, __shfl_xor(m, 2));
                m = fmaxf(m, __shfl_xor(m, 4));
                float p = __expf(lg2[T][r] - m);
                float ss = p;
                ss += __shfl_xor(ss, 1); ss += __shfl_xor(ss, 2); ss += __shfl_xor(ss, 4);
                pp[r] = p * (1.0f / ss);
            }
        }
        // in-register transpose: pa[e] = p[s=l15][n = 8*qt + e]
        float paf[8];
        #pragma unroll
        for (int r = 0; r < 4; ++r) {
            float a0 = __shfl(p0[r], srcA);
            float a1 = __shfl(p1[r], srcA);
            float c0 = __shfl(p0[r], srcA + 16);
            float c1 = __shfl(p1[r], srcA + 16);
            paf[r]     = hi ? a1 : a0;
            paf[r + 4] = hi ? c1 : c0;
        }
        bf16x8 pa;
        #pragma unroll
        for (int e = 0; e < 8; ++e) {
            __bf16 bb = (__bf16)paf[e];
            pa[e] = bb;
            nacc += (float)bb;   // rounded p for norm consistency with PV
        }
        #pragma unroll
        for (int dg = 0; dg < 8; ++dg)
            acc[dg] = __builtin_amdgcn_mfma_f32_16x16x32_bf16(pa, bvf[dg], acc[dg], 0, 0, 0);
    }

    // norm: sum across quads (same l15 = slot)
    nacc += __shfl_xor(nacc, 16);
    nacc += __shfl_xor(nacc, 32);
    if (lane < 8) nsh[w][lane] = nacc;
    // PV D layout: lane holds slots q*4+r (q<2 real) at d = dg*16 + l15
    if (q < 2) {
        #pragma unroll
        for (int dg = 0; dg < 8; ++dg)
            #pragma unroll
            for (int r = 0; r < 4; ++r)
                ush[w][q * 4 + r][dg * 16 + l15] = acc[dg][r];
    }
    __syncthreads();
    if (t < 256) {
        int s = t >> 5, d0 = (t & 31) * 4;
        float4 sum = {0.f, 0.f, 0.f, 0.f};
        #pragma unroll
        for (int w8 = 0; w8 < 8; ++w8) {
            float4 vv = *(const float4*)&ush[w8][s][d0];
            sum.x += vv.x; sum.y += vv.y; sum.z += vv.z; sum.w += vv.w;
        }
        *(float4*)&upart[((size_t)chunk * 512 + b * 8 + s) * 128 + d0] = sum;
    }
    if (t < 8) {
        float sn = 0.f;
        #pragma unroll
        for (int w8 = 0; w8 < 8; ++w8) sn += nsh[w8][t];
        npart[chunk * 512 + b * 8 + t] = sn;
    }
}

// ---------------------------------------------------------------------------
// K4: sum partials -> GRU -> LN -> MLP -> residual (+ fused next-iter q).
// 512 blocks x 256 thr, one (b,s) row per block.
__global__ __launch_bounds__(256) void k_update3(
    const float* __restrict__ slots,
    const float* __restrict__ upart, const float* __restrict__ npart,
    const float* __restrict__ wih, const float* __restrict__ whh,
    const float* __restrict__ bih, const float* __restrict__ bhh,
    const float* __restrict__ mlg, const float* __restrict__ mlb,
    const float* __restrict__ w1, const float* __restrict__ b1,
    const float* __restrict__ w2, const float* __restrict__ b2,
    const float* __restrict__ ns_g, const float* __restrict__ ns_b,
    const float* __restrict__ wq, const float* __restrict__ bq,
    float* __restrict__ outp, ushort_t* __restrict__ qb, int do_q)
{
    __shared__ float us[128];
    __shared__ float hs[128];
    __shared__ float gs[768];
    __shared__ float hnw[128];
    __shared__ float lns[128];
    __shared__ float h1s[256];
    const int t = threadIdx.x;
    const int bs = blockIdx.x;  // 0..511

    if (t < 128) {
        float u = 0.f;
        #pragma unroll
        for (int c = 0; c < 8; ++c) u += upart[((size_t)(c * 512 + bs)) * 128 + t];
        float nsum = 0.f;
        #pragma unroll
        for (int c = 0; c < 8; ++c) nsum += npart[c * 512 + bs];
        us[t] = u / fmaxf(nsum, 1e-8f);
        hs[t] = slots[(size_t)bs * Dn + t];
    }
    __syncthreads();

    #pragma unroll
    for (int jj = 0; jj < 3; ++jj) {
        int j = t + jj * 256;
        const float* W = (j < 384) ? (wih + (size_t)j * Dn) : (whh + (size_t)(j - 384) * Dn);
        const float* X = (j < 384) ? us : hs;
        float a = 0.f;
        #pragma unroll 8
        for (int d = 0; d < 128; d += 4)
            a += dot4(*(const float4*)(W + d), *(const float4*)(X + d));
        gs[j] = a;
    }
    __syncthreads();

    if (t < 64) {
        float hnew[2];
        #pragma unroll
        for (int e = 0; e < 2; ++e) {
            int i = t + e * 64;
            float ir = gs[i]       + bih[i],       hr = gs[384 + i] + bhh[i];
            float iz = gs[128 + i] + bih[128 + i], hz = gs[512 + i] + bhh[128 + i];
            float in_= gs[256 + i] + bih[256 + i], hn = gs[640 + i] + bhh[256 + i];
            float r = 1.0f / (1.0f + __expf(-(ir + hr)));
            float z = 1.0f / (1.0f + __expf(-(iz + hz)));
            float n = tanhf(in_ + r * hn);
            hnew[e] = (1.0f - z) * n + z * hs[i];
        }
        float s  = hnew[0] + hnew[1];
        float sq = hnew[0]*hnew[0] + hnew[1]*hnew[1];
        #pragma unroll
        for (int m = 1; m <= 32; m <<= 1) { s += __shfl_xor(s, m); sq += __shfl_xor(sq, m); }
        float mu = s * (1.0f / 128.0f);
        float rs = rsqrtf(sq * (1.0f / 128.0f) - mu * mu + LN_EPS);
        #pragma unroll
        for (int e = 0; e < 2; ++e) {
            int i = t + e * 64;
            hnw[i] = hnew[e];
            lns[i] = (hnew[e] - mu) * rs * mlg[i] + mlb[i];
        }
    }
    __syncthreads();

    {
        const float* W = w1 + (size_t)t * Dn;
        float a = 0.f;
        #pragma unroll 8
        for (int d = 0; d < 128; d += 4)
            a += dot4(*(const float4*)(W + d), *(const float4*)&lns[d]);
        float x = a + b1[t];
        h1s[t] = 0.5f * x * (1.0f + erff(x * 0.70710678118654752f));
    }
    __syncthreads();

    if (t < 128) {
        const float* W = w2 + (size_t)t * Hn;
        float a = 0.f;
        #pragma unroll 8
        for (int d = 0; d < 256; d += 4)
            a += dot4(*(const float4*)(W + d), *(const float4*)&h1s[d]);
        float o = hnw[t] + a + b2[t];
        outp[(size_t)bs * Dn + t] = o;
        us[t] = o;  // reuse for q-LN
    }
    if (do_q) {
        __syncthreads();
        if (t < 64) {
            float v0 = us[t], v1 = us[t + 64];
            float s  = v0 + v1;
            float sq = v0*v0 + v1*v1;
            #pragma unroll
            for (int m = 1; m <= 32; m <<= 1) { s += __shfl_xor(s, m); sq += __shfl_xor(sq, m); }
            float mu = s * (1.0f / 128.0f);
            float rs = rsqrtf(sq * (1.0f / 128.0f) - mu * mu + LN_EPS);
            lns[t]      = (v0 - mu) * rs * ns_g[t]      + ns_b[t];
            lns[t + 64] = (v1 - mu) * rs * ns_g[t + 64] + ns_b[t + 64];
        }
        __syncthreads();
        if (t < 128) {
            const float* W = wq + (size_t)t * Dn;
            float a = 0.f;
            #pragma unroll 8
            for (int d = 0; d < 128; d += 4)
                a += dot4(*(const float4*)(W + d), *(const float4*)&lns[d]);
            qb[(size_t)bs * Dn + t] = f2bf((a + bq[t]) * QSCALE);
        }
    }
}

// ---------------------------------------------------------------------------
extern "C" void kernel_launch(void* const* d_in, const int* in_sizes, int n_in,
                              void* d_out, int out_size, void* d_ws, size_t ws_size,
                              hipStream_t stream) {
    (void)in_sizes; (void)n_in; (void)out_size; (void)ws_size;
    const float* inputs   = (const float*)d_in[0];
    const float* noise    = (const float*)d_in[1];
    const float* slots_mu = (const float*)d_in[2];
    const float* slots_ls = (const float*)d_in[3];
    const float* wq  = (const float*)d_in[4];
    const float* bq  = (const float*)d_in[5];
    const float* wk  = (const float*)d_in[6];
    const float* bk  = (const float*)d_in[7];
    const float* wv  = (const float*)d_in[8];
    const float* bv  = (const float*)d_in[9];
    const float* gwih = (const float*)d_in[10];
    const float* gwhh = (const float*)d_in[11];
    const float* gbih = (const float*)d_in[12];
    const float* gbhh = (const float*)d_in[13];
    const float* ns_g = (const float*)d_in[14];
    const float* ns_b = (const float*)d_in[15];
    const float* ni_g = (const float*)d_in[16];
    const float* ni_b = (const float*)d_in[17];
    const float* mlg  = (const float*)d_in[18];
    const float* mlb  = (const float*)d_in[19];
    const float* mw1  = (const float*)d_in[20];
    const float* mb1  = (const float*)d_in[21];
    const float* mw2  = (const float*)d_in[22];
    const float* mb2  = (const float*)d_in[23];

    float* ws      = (float*)d_ws;
    float* slots   = ws;                            // 0 .. 65536
    float* upart   = ws + 65536;                    // 65536 .. 589824 (8*512*128)
    float* npart   = ws + 589824;                   // 589824 .. 593920 (4096)
    ushort_t* qb    = (ushort_t*)(ws + 593920);     // 65536 bf16 (32768 f)
    ushort_t* wallT = (ushort_t*)(ws + 626688);     // 32768 bf16 (16384 f)
    ushort_t* kbuf  = (ushort_t*)(ws + 643072);     // 33554432 bf16 (frag order)
    ushort_t* vtbuf = kbuf + 33554432;              // 33554432 bf16 (frag order)

    k_slots_init<<<4, 256, 0, stream>>>(slots_mu, slots_ls, noise, slots);
    k_wprep<<<128, 256, 0, stream>>>(wk, wv, wallT);
    k_lnkv_mfma<<<2048, 512, 0, stream>>>(inputs, ni_g, ni_b, wallT, bk, bv, kbuf, vtbuf);
    k_qproj2<<<64, 256, 0, stream>>>(slots, ns_g, ns_b, wq, bq, qb);
    for (int iter = 0; iter < 3; ++iter) {
        k_attn_mfma<<<dim3(8, 64), 512, 0, stream>>>(kbuf, vtbuf, qb, upart, npart);
        float* outp = (iter == 2) ? (float*)d_out : slots;
        k_update3<<<512, 256, 0, stream>>>(slots, upart, npart, gwih, gwhh, gbih, gbhh,
                                           mlg, mlb, mw1, mb1, mw2, mb2, ns_g, ns_b, wq, bq,
                                           outp, qb, (iter == 2) ? 0 : 1);
    }
}